// Round 10
// baseline (407.294 us; speedup 1.0000x reference)
//
#include <hip/hip_runtime.h>

#define N_NODES 100000
#define N_CH 16
#define DIM 3
#define N_EDGES 1600000
#define N_STEPS 2
// float32 machine eps (reference wraps jnp.finfo(float32).eps)
#define EPS_D 1.1920928955078125e-7

#define PB 1024
#define NBLK ((N_NODES + PB - 1) / PB)   // 98
#define DBINS 64

// ===========================================================================
// CSR build (fused): hist -> (partials+degree-hist) -> (mid-scan+bin-scan)
//                    -> (apply+perm-scatter) -> edge scatter
// ===========================================================================
__global__ void hist_kernel(const int4* __restrict__ senders4,
                            int* __restrict__ cnt) {
    int e = blockIdx.x * blockDim.x + threadIdx.x;
    if (e < N_EDGES / 4) {
        int4 s = senders4[e];
        atomicAdd(&cnt[s.x], 1);
        atomicAdd(&cnt[s.y], 1);
        atomicAdd(&cnt[s.z], 1);
        atomicAdd(&cnt[s.w], 1);
    }
}

// per-block sums of cnt + degree histogram (fused)
__global__ void scan_partials_dhist(const int* __restrict__ cnt,
                                    int* __restrict__ part,
                                    int* __restrict__ bins) {
    __shared__ int sh[PB];
    __shared__ int lb[DBINS];
    int t = threadIdx.x;
    if (t < DBINS) lb[t] = 0;
    int g = blockIdx.x * PB + t;
    int v = (g < N_NODES) ? cnt[g] : 0;
    sh[t] = v;
    __syncthreads();
    for (int off = PB / 2; off > 0; off >>= 1) {
        if (t < off) sh[t] += sh[t + off];
        __syncthreads();
    }
    if (t == 0) part[blockIdx.x] = sh[0];
    if (g < N_NODES) {
        int d = (v > DBINS - 1) ? (DBINS - 1) : v;
        atomicAdd(&lb[d], 1);
    }
    __syncthreads();
    if (t < DBINS && lb[t]) atomicAdd(&bins[t], lb[t]);
}

// single block: exclusive-scan the NBLK partials + exclusive-scan bins (fused)
__global__ void scan_mid_fused(int* __restrict__ part,
                               int* __restrict__ rowptr,
                               const int* __restrict__ bins,
                               int* __restrict__ binoff,
                               int* __restrict__ binfill) {
    __shared__ int sh[128];
    int t = threadIdx.x;
    int v = (t < NBLK) ? part[t] : 0;
    sh[t] = v;
    __syncthreads();
    for (int off = 1; off < 128; off <<= 1) {
        int u = (t >= off) ? sh[t - off] : 0;
        __syncthreads();
        sh[t] += u;
        __syncthreads();
    }
    if (t < NBLK) part[t] = sh[t] - v;
    if (t == NBLK - 1) rowptr[N_NODES] = sh[t];
    // bins scan on wave 0 (independent arrays, no extra sync needed)
    if (t < DBINS) {
        int bv = bins[t];
        int s = bv;
        for (int off = 1; off < DBINS; off <<= 1) {
            int u = __shfl_up(s, off, 64);
            if (t >= off) s += u;
        }
        binoff[t] = s - bv;
        binfill[t] = 0;
    }
}

// rowptr apply + degree-sorted perm scatter (fused)
__global__ void scan_apply_dscatter(const int* __restrict__ cnt,
                                    const int* __restrict__ part,
                                    int* __restrict__ rowptr,
                                    const int* __restrict__ binoff,
                                    int* __restrict__ binfill,
                                    int* __restrict__ perm) {
    __shared__ int sh[PB];
    __shared__ int lcnt[DBINS];
    __shared__ int lbase[DBINS];
    int t = threadIdx.x;
    if (t < DBINS) lcnt[t] = 0;
    int g = blockIdx.x * PB + t;
    int v = (g < N_NODES) ? cnt[g] : 0;
    sh[t] = v;
    __syncthreads();
    for (int off = 1; off < PB; off <<= 1) {
        int u = (t >= off) ? sh[t - off] : 0;
        __syncthreads();
        sh[t] += u;
        __syncthreads();
    }
    if (g < N_NODES) rowptr[g] = part[blockIdx.x] + sh[t] - v;
    int d = 0, myoff = 0;
    if (g < N_NODES) {
        d = (v > DBINS - 1) ? (DBINS - 1) : v;
        myoff = atomicAdd(&lcnt[d], 1);
    }
    __syncthreads();
    if (t < DBINS && lcnt[t]) lbase[t] = atomicAdd(&binfill[t], lcnt[t]);
    __syncthreads();
    if (g < N_NODES && perm) perm[binoff[d] + lbase[d] + myoff] = g;
}

// edge scatter: consumes cnt by atomic decrement (no fill memset needed)
__global__ void scatter_kernel(const int* __restrict__ senders,
                               const int* __restrict__ receivers,
                               const float* __restrict__ weights,
                               const int* __restrict__ rowptr,
                               int* __restrict__ cnt,
                               int2* __restrict__ edata) {
    int e = blockIdx.x * blockDim.x + threadIdx.x;
    if (e >= N_EDGES) return;
    int s = senders[e];
    int old = atomicAdd(&cnt[s], -1);
    edata[rowptr[s] + old - 1] = make_int2(receivers[e], __float_as_int(weights[e]));
}

// ===========================================================================
// fast fp64 rsqrt: fp32 seed + one fp64 Newton (rel err ~3e-14)
// ===========================================================================
__device__ __forceinline__ double fast_rsqrt(double x) {
    double y = (double)rsqrtf((float)x);
    y = y * fma(-0.5 * x, y * y, 1.5);
    return y;
}

// f0(cd) = acos(cd)/sqrt(1-cd^2), fp64, rel err < ~2e-9 (benign region) and
// ~1e-13 near |cd|=1 (the amplification-critical region, z->0).
// NUMERICS FROZEN since round 7.
__device__ __forceinline__ double theta_over_sin(double cd) {
    double acd = fabs(cd);
    bool mid = (acd <= 0.5);
    double z = mid ? (cd * cd) : (0.5 * (1.0 - acd));   // z in [0, 0.25]
    double A = 0.008390335809943149;                    // asin(sqrt(z))/sqrt(z)
    A = fma(A, z, 0.009761609529194078);
    A = fma(A, z, 0.011551800896139706);
    A = fma(A, z, 0.013964843750);
    A = fma(A, z, 0.017352764423076924);
    A = fma(A, z, 0.022372159090909092);
    A = fma(A, z, 0.030381944444444444);
    A = fma(A, z, 0.044642857142857144);
    A = fma(A, z, 0.075);
    A = fma(A, z, 0.16666666666666666);
    A = fma(A, z, 1.0);
    double R = fast_rsqrt(1.0 - z);
    if (mid) return (1.5707963267948966 - cd * A) * R;
    double AR = A * R;
    if (cd > 0.0) return AR;
    double Rz = fast_rsqrt(z);
    return fma(1.5707963267948966 * Rz, R, -AR);
}

// ===========================================================================
// Fused flow step: 4 nodes per wave, lane = c + 16*q.
// Round-7 plain loop (110 us measured — both pipelining attempts regressed).
// Changes vs r7: (a) longest-job-first — perm is ascending-degree, so index
// it reversed: heavy blocks launch first, light blocks pack the tail;
// (b) non-temporal edata load (streamed once; keep L2 for x gathers).
// Per-node numerics identical -> absmax frozen.
// ===========================================================================
template <typename TI, typename TO>
__global__ void flow_kernel(const TI* __restrict__ x,
                            const int* __restrict__ rowptr,
                            const int2* __restrict__ edata,
                            const int* __restrict__ perm,
                            const float* __restrict__ t_sqrt,
                            const float* __restrict__ alpha_sqrt,
                            const float* __restrict__ beta_sqrt,
                            TO* __restrict__ xout) {
    int wave = threadIdx.x >> 6;                  // 4 waves / block
    int lane = threadIdx.x & 63;
    int q = lane >> 4;
    int c = lane & 15;
    int slot = (blockIdx.x * 4 + wave) * 4 + q;   // 16 nodes / block, exact
    int i = perm ? perm[N_NODES - 1 - slot] : slot;   // descending degree

    int beg = rowptr[i];
    int end = rowptr[i + 1];

    const TI* xi = x + ((size_t)i * N_CH + c) * DIM;
    double ax = (double)xi[0], ay = (double)xi[1], az = (double)xi[2];

    double sx = 0.0, sy = 0.0, sz = 0.0, sw = 0.0;
    for (int k = beg; k < end; ++k) {
        long long edl = __builtin_nontemporal_load((const long long*)&edata[k]);
        int r = (int)(edl & 0xffffffffll);
        double w = (double)__int_as_float((int)(edl >> 32));
        const TI* xr = x + ((size_t)r * N_CH + c) * DIM;
        double bx = (double)xr[0], by = (double)xr[1], bz = (double)xr[2];

        double cd = ax * bx + ay * by + az * bz;
        cd = fmin(fmax(cd, -1.0 + 1e-7), 1.0 - 1e-7);
        double f = w * theta_over_sin(cd);

        sx += f * (bx - cd * ax);
        sy += f * (by - cd * ay);
        sz += f * (bz - cd * az);
        sw += w;
    }

    double dg = sw + 1e-12;
    double inv = 1.0 / dg;
    double vx = -sx * inv, vy = -sy * inv, vz = -sz * inv;

    double t = (double)t_sqrt[c];     t = (t * t) / (double)N_STEPS;
    double a = (double)alpha_sqrt[c]; a = a * a;
    double b = (double)beta_sqrt[c];  b = b * b;

    double nrm = sqrt(vx * vx + vy * vy + vz * vz + EPS_D);
    double d = 1.0 / (1.0 + exp(-b * (nrm - a)));
    double scale = (nrm * d <= 1.0) ? d : (1.0 / nrm);
    double fs = -scale * t;
    vx *= fs; vy *= fs; vz *= fs;

    double n = sqrt(vx * vx + vy * vy + vz * vz + 1e-16);
    double cn = cos(n);
    double sf = sin(n) / n;

    TO* xo = xout + ((size_t)i * N_CH + c) * DIM;
    xo[0] = (TO)(cn * ax + sf * vx);
    xo[1] = (TO)(cn * ay + sf * vy);
    xo[2] = (TO)(cn * az + sf * vz);
}

// ===========================================================================
// Fallback (round-1 fp32 atomic path, which passed) if d_ws too small
// ===========================================================================
__global__ void deg_kernel(const int* __restrict__ senders,
                           const float* __restrict__ weights,
                           float* __restrict__ deg) {
    int e = blockIdx.x * blockDim.x + threadIdx.x;
    if (e < N_EDGES) atomicAdd(&deg[senders[e]], weights[e]);
}

__global__ void edge_kernel(const float* __restrict__ x,
                            const int* __restrict__ senders,
                            const int* __restrict__ receivers,
                            const float* __restrict__ weights,
                            float* __restrict__ agg) {
    unsigned int tid = blockIdx.x * blockDim.x + threadIdx.x;
    if (tid >= (unsigned int)N_EDGES * N_CH) return;
    unsigned int e = tid >> 4;
    unsigned int c = tid & 15u;
    int s = senders[e];
    int r = receivers[e];
    float w = weights[e];
    const float* xs = x + ((size_t)s * N_CH + c) * DIM;
    const float* xr = x + ((size_t)r * N_CH + c) * DIM;
    float ax = xs[0], ay = xs[1], az = xs[2];
    float bx = xr[0], by = xr[1], bz = xr[2];
    float cd = ax * bx + ay * by + az * bz;
    cd = fminf(fmaxf(cd, -1.0f + 1e-7f), 1.0f - 1e-7f);
    float theta = acosf(cd);
    float sn = sqrtf(fmaxf(1.0f - cd * cd, 0.0f));
    float f = w * theta / sn;
    float* ag = agg + ((size_t)s * N_CH + c) * DIM;
    atomicAdd(&ag[0], f * (bx - cd * ax));
    atomicAdd(&ag[1], f * (by - cd * ay));
    atomicAdd(&ag[2], f * (bz - cd * az));
}

__global__ void node_kernel(const float* __restrict__ xin,
                            const float* __restrict__ agg,
                            const float* __restrict__ deg,
                            const float* __restrict__ t_sqrt,
                            const float* __restrict__ alpha_sqrt,
                            const float* __restrict__ beta_sqrt,
                            float* __restrict__ xout) {
    unsigned int tid = blockIdx.x * blockDim.x + threadIdx.x;
    if (tid >= (unsigned int)N_NODES * N_CH) return;
    unsigned int i = tid >> 4;
    unsigned int c = tid & 15u;
    float dg = deg[i] + 1e-12f;
    const float* ag = agg + (size_t)tid * DIM;
    float vx = -ag[0] / dg, vy = -ag[1] / dg, vz = -ag[2] / dg;
    float t = t_sqrt[c]; t = (t * t) * (1.0f / N_STEPS);
    float a = alpha_sqrt[c]; a = a * a;
    float b = beta_sqrt[c]; b = b * b;
    float nrm = sqrtf(vx * vx + vy * vy + vz * vz + 1.1920929e-7f);
    float d = 1.0f / (1.0f + __expf(-b * (nrm - a)));
    float scale = (nrm * d <= 1.0f) ? d : (1.0f / nrm);
    float fs = -scale * t;
    vx *= fs; vy *= fs; vz *= fs;
    const float* xi = xin + (size_t)tid * DIM;
    float axx = xi[0], ayy = xi[1], azz = xi[2];
    float n = sqrtf(vx * vx + vy * vy + vz * vz + 1e-16f);
    float cn = cosf(n);
    float sf = sinf(n) / n;
    float* xo = xout + (size_t)tid * DIM;
    xo[0] = cn * axx + sf * vx;
    xo[1] = cn * ayy + sf * vy;
    xo[2] = cn * azz + sf * vz;
}

extern "C" void kernel_launch(void* const* d_in, const int* in_sizes, int n_in,
                              void* d_out, int out_size, void* d_ws, size_t ws_size,
                              hipStream_t stream) {
    const float* nodes      = (const float*)d_in[0];
    const int*   senders    = (const int*)d_in[1];
    const int*   receivers  = (const int*)d_in[2];
    const float* weights    = (const float*)d_in[3];
    const float* t_sqrt     = (const float*)d_in[4];
    const float* alpha_sqrt = (const float*)d_in[5];
    const float* beta_sqrt  = (const float*)d_in[6];
    float* out = (float*)d_out;

    const size_t AL = 255;
    const size_t xtmp_b   = (size_t)N_NODES * N_CH * DIM * sizeof(double);   // 38.4 MB
    const size_t rowptr_b = (((size_t)(N_NODES + 1) * sizeof(int)) + AL) & ~AL;
    const size_t cnt_b    = (((size_t)N_NODES * sizeof(int)) + AL) & ~AL;
    const size_t bins_b   = 1024;   // bins[64]|binoff[64]|binfill[64]|pad
    const size_t part_b   = 4096;
    const size_t perm_b   = (((size_t)N_NODES * sizeof(int)) + AL) & ~AL;
    const size_t edata_b  = (size_t)N_EDGES * sizeof(int2);                  // 12.8 MB
    const size_t need_sorted = xtmp_b + rowptr_b + cnt_b + bins_b + part_b + perm_b + edata_b;
    const size_t need_plain  = xtmp_b + rowptr_b + cnt_b + bins_b + part_b + edata_b;

    if (ws_size >= need_plain) {
        bool sorted = (ws_size >= need_sorted);
        char* p = (char*)d_ws;
        double* xtmp  = (double*)p;           p += xtmp_b;
        int*   rowptr = (int*)p;              p += rowptr_b;
        int*   cnt    = (int*)p;              p += cnt_b;
        int*   bins   = (int*)p;              // [0..63] counts
        int*   binoff = bins + 64;
        int*   binfill= bins + 128;           p += bins_b;
        int*   part   = (int*)p;              p += part_b;
        int*   perm   = nullptr;
        if (sorted) { perm = (int*)p;         p += perm_b; }
        int2*  edata  = (int2*)p;

        // zero cnt + bins[0..63] in one memset (adjacent)
        hipMemsetAsync(cnt, 0, cnt_b + 256, stream);
        hist_kernel<<<(N_EDGES / 4 + 255) / 256, 256, 0, stream>>>(
            (const int4*)senders, cnt);
        scan_partials_dhist<<<NBLK, PB, 0, stream>>>(cnt, part, bins);
        scan_mid_fused<<<1, 128, 0, stream>>>(part, rowptr, bins, binoff, binfill);
        scan_apply_dscatter<<<NBLK, PB, 0, stream>>>(cnt, part, rowptr,
                                                     binoff, binfill, perm);
        // consumes cnt (decrements to zero)
        scatter_kernel<<<(N_EDGES + 255) / 256, 256, 0, stream>>>(
            senders, receivers, weights, rowptr, cnt, edata);

        int grid = N_NODES / 16;   // 6250, exact
        flow_kernel<float, double><<<grid, 256, 0, stream>>>(
            nodes, rowptr, edata, perm, t_sqrt, alpha_sqrt, beta_sqrt, xtmp);
        flow_kernel<double, float><<<grid, 256, 0, stream>>>(
            xtmp, rowptr, edata, perm, t_sqrt, alpha_sqrt, beta_sqrt, out);
    } else {
        // fallback: round-1 fp32 atomic-scatter path (passed at 1.3e-2)
        float* agg = (float*)d_ws;
        float* deg = agg + (size_t)N_NODES * N_CH * DIM;
        hipMemsetAsync(deg, 0, N_NODES * sizeof(float), stream);
        deg_kernel<<<(N_EDGES + 255) / 256, 256, 0, stream>>>(senders, weights, deg);
        const float* xin = nodes;
        for (int step = 0; step < N_STEPS; ++step) {
            hipMemsetAsync(agg, 0, (size_t)N_NODES * N_CH * DIM * sizeof(float), stream);
            unsigned int n_ec = (unsigned int)N_EDGES * N_CH;
            edge_kernel<<<(n_ec + 255) / 256, 256, 0, stream>>>(xin, senders, receivers,
                                                                weights, agg);
            unsigned int n_nc = (unsigned int)N_NODES * N_CH;
            node_kernel<<<(n_nc + 255) / 256, 256, 0, stream>>>(xin, agg, deg, t_sqrt,
                                                                alpha_sqrt, beta_sqrt, out);
            xin = out;
        }
    }
}

// Round 11
// 381.650 us; speedup vs baseline: 1.0672x; 1.0672x over previous
//
#include <hip/hip_runtime.h>

#define N_NODES 100000
#define N_CH 16
#define DIM 3
#define N_EDGES 1600000
#define N_STEPS 2
// float32 machine eps (reference wraps jnp.finfo(float32).eps)
#define EPS_D 1.1920928955078125e-7

#define PB 1024
#define NBLK ((N_NODES + PB - 1) / PB)   // 98
#define DBINS 64

// ===========================================================================
// CSR build (fused, r8-measured): hist -> (partials+degree-hist) ->
// (mid-scan+bin-scan) -> (apply+perm-scatter) -> decrement edge scatter
// ===========================================================================
__global__ void hist_kernel(const int4* __restrict__ senders4,
                            int* __restrict__ cnt) {
    int e = blockIdx.x * blockDim.x + threadIdx.x;
    if (e < N_EDGES / 4) {
        int4 s = senders4[e];
        atomicAdd(&cnt[s.x], 1);
        atomicAdd(&cnt[s.y], 1);
        atomicAdd(&cnt[s.z], 1);
        atomicAdd(&cnt[s.w], 1);
    }
}

// per-block sums of cnt + degree histogram (fused)
__global__ void scan_partials_dhist(const int* __restrict__ cnt,
                                    int* __restrict__ part,
                                    int* __restrict__ bins) {
    __shared__ int sh[PB];
    __shared__ int lb[DBINS];
    int t = threadIdx.x;
    if (t < DBINS) lb[t] = 0;
    int g = blockIdx.x * PB + t;
    int v = (g < N_NODES) ? cnt[g] : 0;
    sh[t] = v;
    __syncthreads();
    for (int off = PB / 2; off > 0; off >>= 1) {
        if (t < off) sh[t] += sh[t + off];
        __syncthreads();
    }
    if (t == 0) part[blockIdx.x] = sh[0];
    if (g < N_NODES) {
        int d = (v > DBINS - 1) ? (DBINS - 1) : v;
        atomicAdd(&lb[d], 1);
    }
    __syncthreads();
    if (t < DBINS && lb[t]) atomicAdd(&bins[t], lb[t]);
}

// single block: exclusive-scan the NBLK partials + exclusive-scan bins (fused)
__global__ void scan_mid_fused(int* __restrict__ part,
                               int* __restrict__ rowptr,
                               const int* __restrict__ bins,
                               int* __restrict__ binoff,
                               int* __restrict__ binfill) {
    __shared__ int sh[128];
    int t = threadIdx.x;
    int v = (t < NBLK) ? part[t] : 0;
    sh[t] = v;
    __syncthreads();
    for (int off = 1; off < 128; off <<= 1) {
        int u = (t >= off) ? sh[t - off] : 0;
        __syncthreads();
        sh[t] += u;
        __syncthreads();
    }
    if (t < NBLK) part[t] = sh[t] - v;
    if (t == NBLK - 1) rowptr[N_NODES] = sh[t];
    // bins scan on wave 0 (independent arrays, no extra sync needed)
    if (t < DBINS) {
        int bv = bins[t];
        int s = bv;
        for (int off = 1; off < DBINS; off <<= 1) {
            int u = __shfl_up(s, off, 64);
            if (t >= off) s += u;
        }
        binoff[t] = s - bv;
        binfill[t] = 0;
    }
}

// rowptr apply + degree-sorted perm scatter (fused)
__global__ void scan_apply_dscatter(const int* __restrict__ cnt,
                                    const int* __restrict__ part,
                                    int* __restrict__ rowptr,
                                    const int* __restrict__ binoff,
                                    int* __restrict__ binfill,
                                    int* __restrict__ perm) {
    __shared__ int sh[PB];
    __shared__ int lcnt[DBINS];
    __shared__ int lbase[DBINS];
    int t = threadIdx.x;
    if (t < DBINS) lcnt[t] = 0;
    int g = blockIdx.x * PB + t;
    int v = (g < N_NODES) ? cnt[g] : 0;
    sh[t] = v;
    __syncthreads();
    for (int off = 1; off < PB; off <<= 1) {
        int u = (t >= off) ? sh[t - off] : 0;
        __syncthreads();
        sh[t] += u;
        __syncthreads();
    }
    if (g < N_NODES) rowptr[g] = part[blockIdx.x] + sh[t] - v;
    int d = 0, myoff = 0;
    if (g < N_NODES) {
        d = (v > DBINS - 1) ? (DBINS - 1) : v;
        myoff = atomicAdd(&lcnt[d], 1);
    }
    __syncthreads();
    if (t < DBINS && lcnt[t]) lbase[t] = atomicAdd(&binfill[t], lcnt[t]);
    __syncthreads();
    if (g < N_NODES && perm) perm[binoff[d] + lbase[d] + myoff] = g;
}

// edge scatter: consumes cnt by atomic decrement (no fill memset needed)
__global__ void scatter_kernel(const int* __restrict__ senders,
                               const int* __restrict__ receivers,
                               const float* __restrict__ weights,
                               const int* __restrict__ rowptr,
                               int* __restrict__ cnt,
                               int2* __restrict__ edata) {
    int e = blockIdx.x * blockDim.x + threadIdx.x;
    if (e >= N_EDGES) return;
    int s = senders[e];
    int old = atomicAdd(&cnt[s], -1);
    edata[rowptr[s] + old - 1] = make_int2(receivers[e], __float_as_int(weights[e]));
}

// ===========================================================================
// fast fp64 rsqrt: fp32 seed + one fp64 Newton (rel err ~3e-14)
// ===========================================================================
__device__ __forceinline__ double fast_rsqrt(double x) {
    double y = (double)rsqrtf((float)x);
    y = y * fma(-0.5 * x, y * y, 1.5);
    return y;
}

// f0(cd) = acos(cd)/sqrt(1-cd^2), fp64, rel err < ~2e-9 (benign region) and
// ~1e-13 near |cd|=1 (the amplification-critical region, z->0).
// NUMERICS FROZEN since round 7.
__device__ __forceinline__ double theta_over_sin(double cd) {
    double acd = fabs(cd);
    bool mid = (acd <= 0.5);
    double z = mid ? (cd * cd) : (0.5 * (1.0 - acd));   // z in [0, 0.25]
    double A = 0.008390335809943149;                    // asin(sqrt(z))/sqrt(z)
    A = fma(A, z, 0.009761609529194078);
    A = fma(A, z, 0.011551800896139706);
    A = fma(A, z, 0.013964843750);
    A = fma(A, z, 0.017352764423076924);
    A = fma(A, z, 0.022372159090909092);
    A = fma(A, z, 0.030381944444444444);
    A = fma(A, z, 0.044642857142857144);
    A = fma(A, z, 0.075);
    A = fma(A, z, 0.16666666666666666);
    A = fma(A, z, 1.0);
    double R = fast_rsqrt(1.0 - z);
    if (mid) return (1.5707963267948966 - cd * A) * R;
    double AR = A * R;
    if (cd > 0.0) return AR;
    double Rz = fast_rsqrt(z);
    return fma(1.5707963267948966 * Rz, R, -AR);
}

// ===========================================================================
// Fused flow step — EXACT round-7 structure (110 us measured; r8 manual
// pipeline 123, r9 unroll-2 117, r10 LJF+nt 122 all regressed — plain loop
// is the compiler's local optimum, do not touch).
// 4 nodes per wave, lane = c + 16*q; ascending-degree perm.
// ===========================================================================
template <typename TI, typename TO>
__global__ void flow_kernel(const TI* __restrict__ x,
                            const int* __restrict__ rowptr,
                            const int2* __restrict__ edata,
                            const int* __restrict__ perm,
                            const float* __restrict__ t_sqrt,
                            const float* __restrict__ alpha_sqrt,
                            const float* __restrict__ beta_sqrt,
                            TO* __restrict__ xout) {
    int wave = threadIdx.x >> 6;                  // 4 waves / block
    int lane = threadIdx.x & 63;
    int q = lane >> 4;
    int c = lane & 15;
    int slot = (blockIdx.x * 4 + wave) * 4 + q;   // 16 nodes / block, exact
    int i = perm ? perm[slot] : slot;

    int beg = rowptr[i];
    int end = rowptr[i + 1];

    const TI* xi = x + ((size_t)i * N_CH + c) * DIM;
    double ax = (double)xi[0], ay = (double)xi[1], az = (double)xi[2];

    double sx = 0.0, sy = 0.0, sz = 0.0, sw = 0.0;
    for (int k = beg; k < end; ++k) {
        int2 ed = edata[k];
        int r = ed.x;
        double w = (double)__int_as_float(ed.y);
        const TI* xr = x + ((size_t)r * N_CH + c) * DIM;
        double bx = (double)xr[0], by = (double)xr[1], bz = (double)xr[2];

        double cd = ax * bx + ay * by + az * bz;
        cd = fmin(fmax(cd, -1.0 + 1e-7), 1.0 - 1e-7);
        double f = w * theta_over_sin(cd);

        sx += f * (bx - cd * ax);
        sy += f * (by - cd * ay);
        sz += f * (bz - cd * az);
        sw += w;
    }

    double dg = sw + 1e-12;
    double inv = 1.0 / dg;
    double vx = -sx * inv, vy = -sy * inv, vz = -sz * inv;

    double t = (double)t_sqrt[c];     t = (t * t) / (double)N_STEPS;
    double a = (double)alpha_sqrt[c]; a = a * a;
    double b = (double)beta_sqrt[c];  b = b * b;

    double nrm = sqrt(vx * vx + vy * vy + vz * vz + EPS_D);
    double d = 1.0 / (1.0 + exp(-b * (nrm - a)));
    double scale = (nrm * d <= 1.0) ? d : (1.0 / nrm);
    double fs = -scale * t;
    vx *= fs; vy *= fs; vz *= fs;

    double n = sqrt(vx * vx + vy * vy + vz * vz + 1e-16);
    double cn = cos(n);
    double sf = sin(n) / n;

    TO* xo = xout + ((size_t)i * N_CH + c) * DIM;
    xo[0] = (TO)(cn * ax + sf * vx);
    xo[1] = (TO)(cn * ay + sf * vy);
    xo[2] = (TO)(cn * az + sf * vz);
}

// ===========================================================================
// Fallback (round-1 fp32 atomic path, which passed) if d_ws too small
// ===========================================================================
__global__ void deg_kernel(const int* __restrict__ senders,
                           const float* __restrict__ weights,
                           float* __restrict__ deg) {
    int e = blockIdx.x * blockDim.x + threadIdx.x;
    if (e < N_EDGES) atomicAdd(&deg[senders[e]], weights[e]);
}

__global__ void edge_kernel(const float* __restrict__ x,
                            const int* __restrict__ senders,
                            const int* __restrict__ receivers,
                            const float* __restrict__ weights,
                            float* __restrict__ agg) {
    unsigned int tid = blockIdx.x * blockDim.x + threadIdx.x;
    if (tid >= (unsigned int)N_EDGES * N_CH) return;
    unsigned int e = tid >> 4;
    unsigned int c = tid & 15u;
    int s = senders[e];
    int r = receivers[e];
    float w = weights[e];
    const float* xs = x + ((size_t)s * N_CH + c) * DIM;
    const float* xr = x + ((size_t)r * N_CH + c) * DIM;
    float ax = xs[0], ay = xs[1], az = xs[2];
    float bx = xr[0], by = xr[1], bz = xr[2];
    float cd = ax * bx + ay * by + az * bz;
    cd = fminf(fmaxf(cd, -1.0f + 1e-7f), 1.0f - 1e-7f);
    float theta = acosf(cd);
    float sn = sqrtf(fmaxf(1.0f - cd * cd, 0.0f));
    float f = w * theta / sn;
    float* ag = agg + ((size_t)s * N_CH + c) * DIM;
    atomicAdd(&ag[0], f * (bx - cd * ax));
    atomicAdd(&ag[1], f * (by - cd * ay));
    atomicAdd(&ag[2], f * (bz - cd * az));
}

__global__ void node_kernel(const float* __restrict__ xin,
                            const float* __restrict__ agg,
                            const float* __restrict__ deg,
                            const float* __restrict__ t_sqrt,
                            const float* __restrict__ alpha_sqrt,
                            const float* __restrict__ beta_sqrt,
                            float* __restrict__ xout) {
    unsigned int tid = blockIdx.x * blockDim.x + threadIdx.x;
    if (tid >= (unsigned int)N_NODES * N_CH) return;
    unsigned int i = tid >> 4;
    unsigned int c = tid & 15u;
    float dg = deg[i] + 1e-12f;
    const float* ag = agg + (size_t)tid * DIM;
    float vx = -ag[0] / dg, vy = -ag[1] / dg, vz = -ag[2] / dg;
    float t = t_sqrt[c]; t = (t * t) * (1.0f / N_STEPS);
    float a = alpha_sqrt[c]; a = a * a;
    float b = beta_sqrt[c]; b = b * b;
    float nrm = sqrtf(vx * vx + vy * vy + vz * vz + 1.1920929e-7f);
    float d = 1.0f / (1.0f + __expf(-b * (nrm - a)));
    float scale = (nrm * d <= 1.0f) ? d : (1.0f / nrm);
    float fs = -scale * t;
    vx *= fs; vy *= fs; vz *= fs;
    const float* xi = xin + (size_t)tid * DIM;
    float axx = xi[0], ayy = xi[1], azz = xi[2];
    float n = sqrtf(vx * vx + vy * vy + vz * vz + 1e-16f);
    float cn = cosf(n);
    float sf = sinf(n) / n;
    float* xo = xout + (size_t)tid * DIM;
    xo[0] = cn * axx + sf * vx;
    xo[1] = cn * ayy + sf * vy;
    xo[2] = cn * azz + sf * vz;
}

extern "C" void kernel_launch(void* const* d_in, const int* in_sizes, int n_in,
                              void* d_out, int out_size, void* d_ws, size_t ws_size,
                              hipStream_t stream) {
    const float* nodes      = (const float*)d_in[0];
    const int*   senders    = (const int*)d_in[1];
    const int*   receivers  = (const int*)d_in[2];
    const float* weights    = (const float*)d_in[3];
    const float* t_sqrt     = (const float*)d_in[4];
    const float* alpha_sqrt = (const float*)d_in[5];
    const float* beta_sqrt  = (const float*)d_in[6];
    float* out = (float*)d_out;

    const size_t AL = 255;
    const size_t xtmp_b   = (size_t)N_NODES * N_CH * DIM * sizeof(double);   // 38.4 MB
    const size_t rowptr_b = (((size_t)(N_NODES + 1) * sizeof(int)) + AL) & ~AL;
    const size_t cnt_b    = (((size_t)N_NODES * sizeof(int)) + AL) & ~AL;
    const size_t bins_b   = 1024;   // bins[64]|binoff[64]|binfill[64]|pad
    const size_t part_b   = 4096;
    const size_t perm_b   = (((size_t)N_NODES * sizeof(int)) + AL) & ~AL;
    const size_t edata_b  = (size_t)N_EDGES * sizeof(int2);                  // 12.8 MB
    const size_t need_sorted = xtmp_b + rowptr_b + cnt_b + bins_b + part_b + perm_b + edata_b;
    const size_t need_plain  = xtmp_b + rowptr_b + cnt_b + bins_b + part_b + edata_b;

    if (ws_size >= need_plain) {
        bool sorted = (ws_size >= need_sorted);
        char* p = (char*)d_ws;
        double* xtmp  = (double*)p;           p += xtmp_b;
        int*   rowptr = (int*)p;              p += rowptr_b;
        int*   cnt    = (int*)p;              p += cnt_b;
        int*   bins   = (int*)p;              // [0..63] counts
        int*   binoff = bins + 64;
        int*   binfill= bins + 128;           p += bins_b;
        int*   part   = (int*)p;              p += part_b;
        int*   perm   = nullptr;
        if (sorted) { perm = (int*)p;         p += perm_b; }
        int2*  edata  = (int2*)p;

        // zero cnt + bins[0..63] in one memset (adjacent)
        hipMemsetAsync(cnt, 0, cnt_b + 256, stream);
        hist_kernel<<<(N_EDGES / 4 + 255) / 256, 256, 0, stream>>>(
            (const int4*)senders, cnt);
        scan_partials_dhist<<<NBLK, PB, 0, stream>>>(cnt, part, bins);
        scan_mid_fused<<<1, 128, 0, stream>>>(part, rowptr, bins, binoff, binfill);
        scan_apply_dscatter<<<NBLK, PB, 0, stream>>>(cnt, part, rowptr,
                                                     binoff, binfill, perm);
        // consumes cnt (decrements to zero)
        scatter_kernel<<<(N_EDGES + 255) / 256, 256, 0, stream>>>(
            senders, receivers, weights, rowptr, cnt, edata);

        int grid = N_NODES / 16;   // 6250, exact
        flow_kernel<float, double><<<grid, 256, 0, stream>>>(
            nodes, rowptr, edata, perm, t_sqrt, alpha_sqrt, beta_sqrt, xtmp);
        flow_kernel<double, float><<<grid, 256, 0, stream>>>(
            xtmp, rowptr, edata, perm, t_sqrt, alpha_sqrt, beta_sqrt, out);
    } else {
        // fallback: round-1 fp32 atomic-scatter path (passed at 1.3e-2)
        float* agg = (float*)d_ws;
        float* deg = agg + (size_t)N_NODES * N_CH * DIM;
        hipMemsetAsync(deg, 0, N_NODES * sizeof(float), stream);
        deg_kernel<<<(N_EDGES + 255) / 256, 256, 0, stream>>>(senders, weights, deg);
        const float* xin = nodes;
        for (int step = 0; step < N_STEPS; ++step) {
            hipMemsetAsync(agg, 0, (size_t)N_NODES * N_CH * DIM * sizeof(float), stream);
            unsigned int n_ec = (unsigned int)N_EDGES * N_CH;
            edge_kernel<<<(n_ec + 255) / 256, 256, 0, stream>>>(xin, senders, receivers,
                                                                weights, agg);
            unsigned int n_nc = (unsigned int)N_NODES * N_CH;
            node_kernel<<<(n_nc + 255) / 256, 256, 0, stream>>>(xin, agg, deg, t_sqrt,
                                                                alpha_sqrt, beta_sqrt, out);
            xin = out;
        }
    }
}

// Round 12
// 354.653 us; speedup vs baseline: 1.1484x; 1.0761x over previous
//
#include <hip/hip_runtime.h>

#define N_NODES 100000
#define N_CH 16
#define DIM 3
#define N_EDGES 1600000
#define N_STEPS 2
// float32 machine eps (reference wraps jnp.finfo(float32).eps)
#define EPS_D 1.1920928955078125e-7

#define PB 1024
#define NBLK ((N_NODES + PB - 1) / PB)   // 98
#define DBINS 64
#define NBUCK 256                        // sender buckets of 512 nodes (195 live)
#define TA 4096                          // edges per block, bucket pass
#define NBLK_A ((N_EDGES + TA - 1) / TA) // 391
#define NBLK_B 2048                      // fine-scatter blocks (XCD-swizzled)

// ===========================================================================
// CSR build: hist -> (partials+degree-hist) -> (mid-scan+bin-scan)
//            -> (apply + perm-scatter + bucket-base harvest)
//            -> bucket scatter (pass A) -> fine scatter (pass B)
// ===========================================================================
__global__ void hist_kernel(const int4* __restrict__ senders4,
                            int* __restrict__ cnt) {
    int e = blockIdx.x * blockDim.x + threadIdx.x;
    if (e < N_EDGES / 4) {
        int4 s = senders4[e];
        atomicAdd(&cnt[s.x], 1);
        atomicAdd(&cnt[s.y], 1);
        atomicAdd(&cnt[s.z], 1);
        atomicAdd(&cnt[s.w], 1);
    }
}

// per-block sums of cnt + degree histogram (fused)
__global__ void scan_partials_dhist(const int* __restrict__ cnt,
                                    int* __restrict__ part,
                                    int* __restrict__ bins) {
    __shared__ int sh[PB];
    __shared__ int lb[DBINS];
    int t = threadIdx.x;
    if (t < DBINS) lb[t] = 0;
    int g = blockIdx.x * PB + t;
    int v = (g < N_NODES) ? cnt[g] : 0;
    sh[t] = v;
    __syncthreads();
    for (int off = PB / 2; off > 0; off >>= 1) {
        if (t < off) sh[t] += sh[t + off];
        __syncthreads();
    }
    if (t == 0) part[blockIdx.x] = sh[0];
    if (g < N_NODES) {
        int d = (v > DBINS - 1) ? (DBINS - 1) : v;
        atomicAdd(&lb[d], 1);
    }
    __syncthreads();
    if (t < DBINS && lb[t]) atomicAdd(&bins[t], lb[t]);
}

// single block: exclusive-scan the NBLK partials + exclusive-scan bins (fused)
__global__ void scan_mid_fused(int* __restrict__ part,
                               int* __restrict__ rowptr,
                               const int* __restrict__ bins,
                               int* __restrict__ binoff,
                               int* __restrict__ binfill) {
    __shared__ int sh[128];
    int t = threadIdx.x;
    int v = (t < NBLK) ? part[t] : 0;
    sh[t] = v;
    __syncthreads();
    for (int off = 1; off < 128; off <<= 1) {
        int u = (t >= off) ? sh[t - off] : 0;
        __syncthreads();
        sh[t] += u;
        __syncthreads();
    }
    if (t < NBLK) part[t] = sh[t] - v;
    if (t == NBLK - 1) rowptr[N_NODES] = sh[t];
    if (t < DBINS) {
        int bv = bins[t];
        int s = bv;
        for (int off = 1; off < DBINS; off <<= 1) {
            int u = __shfl_up(s, off, 64);
            if (t >= off) s += u;
        }
        binoff[t] = s - bv;
        binfill[t] = 0;
    }
}

// rowptr apply + degree-sorted perm scatter + bucket-base harvest (fused)
__global__ void scan_apply_dscatter(const int* __restrict__ cnt,
                                    const int* __restrict__ part,
                                    int* __restrict__ rowptr,
                                    const int* __restrict__ binoff,
                                    int* __restrict__ binfill,
                                    int* __restrict__ perm,
                                    int* __restrict__ bfill) {
    __shared__ int sh[PB];
    __shared__ int lcnt[DBINS];
    __shared__ int lbase[DBINS];
    int t = threadIdx.x;
    if (t < DBINS) lcnt[t] = 0;
    int g = blockIdx.x * PB + t;
    int v = (g < N_NODES) ? cnt[g] : 0;
    sh[t] = v;
    __syncthreads();
    for (int off = 1; off < PB; off <<= 1) {
        int u = (t >= off) ? sh[t - off] : 0;
        __syncthreads();
        sh[t] += u;
        __syncthreads();
    }
    if (g < N_NODES) {
        int rp = part[blockIdx.x] + sh[t] - v;
        rowptr[g] = rp;
        if ((g & 511) == 0) bfill[g >> 9] = rp;   // bucket base = rowptr[b*512]
    }
    int d = 0, myoff = 0;
    if (g < N_NODES) {
        d = (v > DBINS - 1) ? (DBINS - 1) : v;
        myoff = atomicAdd(&lcnt[d], 1);
    }
    __syncthreads();
    if (t < DBINS && lcnt[t]) lbase[t] = atomicAdd(&binfill[t], lcnt[t]);
    __syncthreads();
    if (g < N_NODES && perm) perm[binoff[d] + lbase[d] + myoff] = g;
}

// pass A: scatter edges into their sender-bucket's CSR region (staging).
// Block-local LDS histogram + rank -> per-(block,bucket) contiguous writes.
__global__ void bucket_scatter(const int* __restrict__ senders,
                               const int* __restrict__ receivers,
                               const float* __restrict__ weights,
                               int* __restrict__ bfill,
                               int* __restrict__ stg_s,
                               int2* __restrict__ stg_rw) {
    __shared__ int lcnt[NBUCK];
    __shared__ int lbase[NBUCK];
    int t = threadIdx.x;              // blockDim == NBUCK == 256
    lcnt[t] = 0;
    __syncthreads();
    int base = blockIdx.x * TA;
    for (int k = t; k < TA; k += 256) {
        int e = base + k;
        if (e < N_EDGES) atomicAdd(&lcnt[senders[e] >> 9], 1);
    }
    __syncthreads();
    int c = lcnt[t];
    if (c) lbase[t] = atomicAdd(&bfill[t], c);
    __syncthreads();
    lcnt[t] = 0;
    __syncthreads();
    for (int k = t; k < TA; k += 256) {
        int e = base + k;
        if (e < N_EDGES) {
            int s = senders[e];
            int b = s >> 9;
            int pos = lbase[b] + atomicAdd(&lcnt[b], 1);
            stg_s[pos] = s;
            stg_rw[pos] = make_int2(receivers[e], __float_as_int(weights[e]));
        }
    }
}

// pass B: fine scatter within buckets. XCD-swizzled so each contiguous 1/8
// of edata (its buckets' 65KB regions) is written by ONE XCD -> lines stay
// resident in that XCD's L2, written back once (kills the 8x write amp).
__global__ void fine_scatter(const int* __restrict__ stg_s,
                             const int2* __restrict__ stg_rw,
                             const int* __restrict__ rowptr,
                             int* __restrict__ cnt,
                             int2* __restrict__ edata) {
    const int CH = (N_EDGES + NBLK_B - 1) / NBLK_B;          // 782
    int bid = blockIdx.x;
    int chunk = (bid & 7) * (NBLK_B / 8) + (bid >> 3);       // XCD = bid%8
    int s0 = chunk * CH;
    int s1 = s0 + CH; if (s1 > N_EDGES) s1 = N_EDGES;
    for (int e = s0 + (int)threadIdx.x; e < s1; e += 256) {
        int s = stg_s[e];
        int old = atomicAdd(&cnt[s], -1);
        edata[rowptr[s] + old - 1] = stg_rw[e];
    }
}

// ===========================================================================
// fast fp64 rsqrt: fp32 seed + one fp64 Newton (rel err ~3e-14)
// ===========================================================================
__device__ __forceinline__ double fast_rsqrt(double x) {
    double y = (double)rsqrtf((float)x);
    y = y * fma(-0.5 * x, y * y, 1.5);
    return y;
}

// f0(cd) = acos(cd)/sqrt(1-cd^2), fp64. NUMERICS FROZEN since round 7.
__device__ __forceinline__ double theta_over_sin(double cd) {
    double acd = fabs(cd);
    bool mid = (acd <= 0.5);
    double z = mid ? (cd * cd) : (0.5 * (1.0 - acd));   // z in [0, 0.25]
    double A = 0.008390335809943149;                    // asin(sqrt(z))/sqrt(z)
    A = fma(A, z, 0.009761609529194078);
    A = fma(A, z, 0.011551800896139706);
    A = fma(A, z, 0.013964843750);
    A = fma(A, z, 0.017352764423076924);
    A = fma(A, z, 0.022372159090909092);
    A = fma(A, z, 0.030381944444444444);
    A = fma(A, z, 0.044642857142857144);
    A = fma(A, z, 0.075);
    A = fma(A, z, 0.16666666666666666);
    A = fma(A, z, 1.0);
    double R = fast_rsqrt(1.0 - z);
    if (mid) return (1.5707963267948966 - cd * A) * R;
    double AR = A * R;
    if (cd > 0.0) return AR;
    double Rz = fast_rsqrt(z);
    return fma(1.5707963267948966 * Rz, R, -AR);
}

// ===========================================================================
// Fused flow step — EXACT round-7 structure (measured local optimum; r8-r10
// pipelining/unroll/nt variants all regressed). 4 nodes/wave, lane = c+16*q.
// ===========================================================================
template <typename TI, typename TO>
__global__ void flow_kernel(const TI* __restrict__ x,
                            const int* __restrict__ rowptr,
                            const int2* __restrict__ edata,
                            const int* __restrict__ perm,
                            const float* __restrict__ t_sqrt,
                            const float* __restrict__ alpha_sqrt,
                            const float* __restrict__ beta_sqrt,
                            TO* __restrict__ xout) {
    int wave = threadIdx.x >> 6;                  // 4 waves / block
    int lane = threadIdx.x & 63;
    int q = lane >> 4;
    int c = lane & 15;
    int slot = (blockIdx.x * 4 + wave) * 4 + q;   // 16 nodes / block, exact
    int i = perm ? perm[slot] : slot;

    int beg = rowptr[i];
    int end = rowptr[i + 1];

    const TI* xi = x + ((size_t)i * N_CH + c) * DIM;
    double ax = (double)xi[0], ay = (double)xi[1], az = (double)xi[2];

    double sx = 0.0, sy = 0.0, sz = 0.0, sw = 0.0;
    for (int k = beg; k < end; ++k) {
        int2 ed = edata[k];
        int r = ed.x;
        double w = (double)__int_as_float(ed.y);
        const TI* xr = x + ((size_t)r * N_CH + c) * DIM;
        double bx = (double)xr[0], by = (double)xr[1], bz = (double)xr[2];

        double cd = ax * bx + ay * by + az * bz;
        cd = fmin(fmax(cd, -1.0 + 1e-7), 1.0 - 1e-7);
        double f = w * theta_over_sin(cd);

        sx += f * (bx - cd * ax);
        sy += f * (by - cd * ay);
        sz += f * (bz - cd * az);
        sw += w;
    }

    double dg = sw + 1e-12;
    double inv = 1.0 / dg;
    double vx = -sx * inv, vy = -sy * inv, vz = -sz * inv;

    double t = (double)t_sqrt[c];     t = (t * t) / (double)N_STEPS;
    double a = (double)alpha_sqrt[c]; a = a * a;
    double b = (double)beta_sqrt[c];  b = b * b;

    double nrm = sqrt(vx * vx + vy * vy + vz * vz + EPS_D);
    double d = 1.0 / (1.0 + exp(-b * (nrm - a)));
    double scale = (nrm * d <= 1.0) ? d : (1.0 / nrm);
    double fs = -scale * t;
    vx *= fs; vy *= fs; vz *= fs;

    double n = sqrt(vx * vx + vy * vy + vz * vz + 1e-16);
    double cn = cos(n);
    double sf = sin(n) / n;

    TO* xo = xout + ((size_t)i * N_CH + c) * DIM;
    xo[0] = (TO)(cn * ax + sf * vx);
    xo[1] = (TO)(cn * ay + sf * vy);
    xo[2] = (TO)(cn * az + sf * vz);
}

// ===========================================================================
// Fallback (round-1 fp32 atomic path, which passed) if d_ws too small
// ===========================================================================
__global__ void deg_kernel(const int* __restrict__ senders,
                           const float* __restrict__ weights,
                           float* __restrict__ deg) {
    int e = blockIdx.x * blockDim.x + threadIdx.x;
    if (e < N_EDGES) atomicAdd(&deg[senders[e]], weights[e]);
}

__global__ void edge_kernel(const float* __restrict__ x,
                            const int* __restrict__ senders,
                            const int* __restrict__ receivers,
                            const float* __restrict__ weights,
                            float* __restrict__ agg) {
    unsigned int tid = blockIdx.x * blockDim.x + threadIdx.x;
    if (tid >= (unsigned int)N_EDGES * N_CH) return;
    unsigned int e = tid >> 4;
    unsigned int c = tid & 15u;
    int s = senders[e];
    int r = receivers[e];
    float w = weights[e];
    const float* xs = x + ((size_t)s * N_CH + c) * DIM;
    const float* xr = x + ((size_t)r * N_CH + c) * DIM;
    float ax = xs[0], ay = xs[1], az = xs[2];
    float bx = xr[0], by = xr[1], bz = xr[2];
    float cd = ax * bx + ay * by + az * bz;
    cd = fminf(fmaxf(cd, -1.0f + 1e-7f), 1.0f - 1e-7f);
    float theta = acosf(cd);
    float sn = sqrtf(fmaxf(1.0f - cd * cd, 0.0f));
    float f = w * theta / sn;
    float* ag = agg + ((size_t)s * N_CH + c) * DIM;
    atomicAdd(&ag[0], f * (bx - cd * ax));
    atomicAdd(&ag[1], f * (by - cd * ay));
    atomicAdd(&ag[2], f * (bz - cd * az));
}

__global__ void node_kernel(const float* __restrict__ xin,
                            const float* __restrict__ agg,
                            const float* __restrict__ deg,
                            const float* __restrict__ t_sqrt,
                            const float* __restrict__ alpha_sqrt,
                            const float* __restrict__ beta_sqrt,
                            float* __restrict__ xout) {
    unsigned int tid = blockIdx.x * blockDim.x + threadIdx.x;
    if (tid >= (unsigned int)N_NODES * N_CH) return;
    unsigned int i = tid >> 4;
    unsigned int c = tid & 15u;
    float dg = deg[i] + 1e-12f;
    const float* ag = agg + (size_t)tid * DIM;
    float vx = -ag[0] / dg, vy = -ag[1] / dg, vz = -ag[2] / dg;
    float t = t_sqrt[c]; t = (t * t) * (1.0f / N_STEPS);
    float a = alpha_sqrt[c]; a = a * a;
    float b = beta_sqrt[c]; b = b * b;
    float nrm = sqrtf(vx * vx + vy * vy + vz * vz + 1.1920929e-7f);
    float d = 1.0f / (1.0f + __expf(-b * (nrm - a)));
    float scale = (nrm * d <= 1.0f) ? d : (1.0f / nrm);
    float fs = -scale * t;
    vx *= fs; vy *= fs; vz *= fs;
    const float* xi = xin + (size_t)tid * DIM;
    float axx = xi[0], ayy = xi[1], azz = xi[2];
    float n = sqrtf(vx * vx + vy * vy + vz * vz + 1e-16f);
    float cn = cosf(n);
    float sf = sinf(n) / n;
    float* xo = xout + (size_t)tid * DIM;
    xo[0] = cn * axx + sf * vx;
    xo[1] = cn * ayy + sf * vy;
    xo[2] = cn * azz + sf * vz;
}

extern "C" void kernel_launch(void* const* d_in, const int* in_sizes, int n_in,
                              void* d_out, int out_size, void* d_ws, size_t ws_size,
                              hipStream_t stream) {
    const float* nodes      = (const float*)d_in[0];
    const int*   senders    = (const int*)d_in[1];
    const int*   receivers  = (const int*)d_in[2];
    const float* weights    = (const float*)d_in[3];
    const float* t_sqrt     = (const float*)d_in[4];
    const float* alpha_sqrt = (const float*)d_in[5];
    const float* beta_sqrt  = (const float*)d_in[6];
    float* out = (float*)d_out;

    const size_t AL = 255;
    const size_t xtmp_b   = (size_t)N_NODES * N_CH * DIM * sizeof(double);   // 38.4 MB
    const size_t rowptr_b = (((size_t)(N_NODES + 1) * sizeof(int)) + AL) & ~AL;
    const size_t cnt_b    = (((size_t)N_NODES * sizeof(int)) + AL) & ~AL;
    const size_t bins_b   = 2048;   // bins[64]|binoff[64]|binfill[64]|bfill[256]
    const size_t part_b   = 4096;
    const size_t perm_b   = (((size_t)N_NODES * sizeof(int)) + AL) & ~AL;
    const size_t edata_b  = (size_t)N_EDGES * sizeof(int2);                  // 12.8 MB
    const size_t need_sorted = xtmp_b + rowptr_b + cnt_b + bins_b + part_b + perm_b + edata_b;
    const size_t need_plain  = xtmp_b + rowptr_b + cnt_b + bins_b + part_b + edata_b;

    if (ws_size >= need_plain) {
        bool sorted = (ws_size >= need_sorted);
        char* p = (char*)d_ws;
        double* xtmp  = (double*)p;           p += xtmp_b;
        int*   rowptr = (int*)p;              p += rowptr_b;
        int*   cnt    = (int*)p;              p += cnt_b;
        int*   bins   = (int*)p;              // [0..63] counts
        int*   binoff = bins + 64;
        int*   binfill= bins + 128;
        int*   bfill  = bins + 192;           p += bins_b;
        int*   part   = (int*)p;              p += part_b;
        int*   perm   = nullptr;
        if (sorted) { perm = (int*)p;         p += perm_b; }
        int2*  edata  = (int2*)p;

        // staging aliases xtmp (dead until flow step 1; pass B completes first)
        int2*  stg_rw = (int2*)xtmp;                         // 12.8 MB
        int*   stg_s  = (int*)((char*)xtmp + edata_b);       //  6.4 MB

        // zero cnt + bins[0..63] in one memset (adjacent; bfill overwritten later)
        hipMemsetAsync(cnt, 0, cnt_b + 256, stream);
        hist_kernel<<<(N_EDGES / 4 + 255) / 256, 256, 0, stream>>>(
            (const int4*)senders, cnt);
        scan_partials_dhist<<<NBLK, PB, 0, stream>>>(cnt, part, bins);
        scan_mid_fused<<<1, 128, 0, stream>>>(part, rowptr, bins, binoff, binfill);
        scan_apply_dscatter<<<NBLK, PB, 0, stream>>>(cnt, part, rowptr,
                                                     binoff, binfill, perm, bfill);
        bucket_scatter<<<NBLK_A, NBUCK, 0, stream>>>(senders, receivers, weights,
                                                     bfill, stg_s, stg_rw);
        // consumes cnt (decrements to zero)
        fine_scatter<<<NBLK_B, 256, 0, stream>>>(stg_s, stg_rw, rowptr, cnt, edata);

        int grid = N_NODES / 16;   // 6250, exact
        flow_kernel<float, double><<<grid, 256, 0, stream>>>(
            nodes, rowptr, edata, perm, t_sqrt, alpha_sqrt, beta_sqrt, xtmp);
        flow_kernel<double, float><<<grid, 256, 0, stream>>>(
            xtmp, rowptr, edata, perm, t_sqrt, alpha_sqrt, beta_sqrt, out);
    } else {
        // fallback: round-1 fp32 atomic-scatter path (passed at 1.3e-2)
        float* agg = (float*)d_ws;
        float* deg = agg + (size_t)N_NODES * N_CH * DIM;
        hipMemsetAsync(deg, 0, N_NODES * sizeof(float), stream);
        deg_kernel<<<(N_EDGES + 255) / 256, 256, 0, stream>>>(senders, weights, deg);
        const float* xin = nodes;
        for (int step = 0; step < N_STEPS; ++step) {
            hipMemsetAsync(agg, 0, (size_t)N_NODES * N_CH * DIM * sizeof(float), stream);
            unsigned int n_ec = (unsigned int)N_EDGES * N_CH;
            edge_kernel<<<(n_ec + 255) / 256, 256, 0, stream>>>(xin, senders, receivers,
                                                                weights, agg);
            unsigned int n_nc = (unsigned int)N_NODES * N_CH;
            node_kernel<<<(n_nc + 255) / 256, 256, 0, stream>>>(xin, agg, deg, t_sqrt,
                                                                alpha_sqrt, beta_sqrt, out);
            xin = out;
        }
    }
}

// Round 13
// 333.523 us; speedup vs baseline: 1.2212x; 1.0634x over previous
//
#include <hip/hip_runtime.h>

#define N_NODES 100000
#define N_CH 16
#define DIM 3
#define N_EDGES 1600000
#define N_STEPS 2
// float32 machine eps (reference wraps jnp.finfo(float32).eps)
#define EPS_D 1.1920928955078125e-7

#define PB 1024
#define NBLK ((N_NODES + PB - 1) / PB)   // 98
#define DBINS 64
#define NBUCK 256                        // sender buckets of 512 nodes (196 live)
#define NBUCK_LIVE ((N_NODES + 511) / 512)   // 196
#define TA 4096                          // edges per block, bucket pass
#define NBLK_A ((N_EDGES + TA - 1) / TA) // 391
#define CAP 14336                        // LDS edge capacity per bucket (114.7 KB)

// ===========================================================================
// CSR build: hist -> (partials+degree-hist) -> (mid-scan+bin-scan)
//            -> (apply + perm-scatter + bucket-base harvest)
//            -> bucket scatter (pass A) -> LDS bucket sort (pass B)
// ===========================================================================
__global__ void hist_kernel(const int4* __restrict__ senders4,
                            int* __restrict__ cnt) {
    int e = blockIdx.x * blockDim.x + threadIdx.x;
    if (e < N_EDGES / 4) {
        int4 s = senders4[e];
        atomicAdd(&cnt[s.x], 1);
        atomicAdd(&cnt[s.y], 1);
        atomicAdd(&cnt[s.z], 1);
        atomicAdd(&cnt[s.w], 1);
    }
}

// per-block sums of cnt + degree histogram (fused)
__global__ void scan_partials_dhist(const int* __restrict__ cnt,
                                    int* __restrict__ part,
                                    int* __restrict__ bins) {
    __shared__ int sh[PB];
    __shared__ int lb[DBINS];
    int t = threadIdx.x;
    if (t < DBINS) lb[t] = 0;
    int g = blockIdx.x * PB + t;
    int v = (g < N_NODES) ? cnt[g] : 0;
    sh[t] = v;
    __syncthreads();
    for (int off = PB / 2; off > 0; off >>= 1) {
        if (t < off) sh[t] += sh[t + off];
        __syncthreads();
    }
    if (t == 0) part[blockIdx.x] = sh[0];
    if (g < N_NODES) {
        int d = (v > DBINS - 1) ? (DBINS - 1) : v;
        atomicAdd(&lb[d], 1);
    }
    __syncthreads();
    if (t < DBINS && lb[t]) atomicAdd(&bins[t], lb[t]);
}

// single block: exclusive-scan the NBLK partials + exclusive-scan bins (fused)
__global__ void scan_mid_fused(int* __restrict__ part,
                               int* __restrict__ rowptr,
                               const int* __restrict__ bins,
                               int* __restrict__ binoff,
                               int* __restrict__ binfill) {
    __shared__ int sh[128];
    int t = threadIdx.x;
    int v = (t < NBLK) ? part[t] : 0;
    sh[t] = v;
    __syncthreads();
    for (int off = 1; off < 128; off <<= 1) {
        int u = (t >= off) ? sh[t - off] : 0;
        __syncthreads();
        sh[t] += u;
        __syncthreads();
    }
    if (t < NBLK) part[t] = sh[t] - v;
    if (t == NBLK - 1) rowptr[N_NODES] = sh[t];
    if (t < DBINS) {
        int bv = bins[t];
        int s = bv;
        for (int off = 1; off < DBINS; off <<= 1) {
            int u = __shfl_up(s, off, 64);
            if (t >= off) s += u;
        }
        binoff[t] = s - bv;
        binfill[t] = 0;
    }
}

// rowptr apply + degree-sorted perm scatter + bucket-base harvest (fused)
__global__ void scan_apply_dscatter(const int* __restrict__ cnt,
                                    const int* __restrict__ part,
                                    int* __restrict__ rowptr,
                                    const int* __restrict__ binoff,
                                    int* __restrict__ binfill,
                                    int* __restrict__ perm,
                                    int* __restrict__ bfill) {
    __shared__ int sh[PB];
    __shared__ int lcnt[DBINS];
    __shared__ int lbase[DBINS];
    int t = threadIdx.x;
    if (t < DBINS) lcnt[t] = 0;
    int g = blockIdx.x * PB + t;
    int v = (g < N_NODES) ? cnt[g] : 0;
    sh[t] = v;
    __syncthreads();
    for (int off = 1; off < PB; off <<= 1) {
        int u = (t >= off) ? sh[t - off] : 0;
        __syncthreads();
        sh[t] += u;
        __syncthreads();
    }
    if (g < N_NODES) {
        int rp = part[blockIdx.x] + sh[t] - v;
        rowptr[g] = rp;
        if ((g & 511) == 0) bfill[g >> 9] = rp;   // bucket base = rowptr[b*512]
    }
    int d = 0, myoff = 0;
    if (g < N_NODES) {
        d = (v > DBINS - 1) ? (DBINS - 1) : v;
        myoff = atomicAdd(&lcnt[d], 1);
    }
    __syncthreads();
    if (t < DBINS && lcnt[t]) lbase[t] = atomicAdd(&binfill[t], lcnt[t]);
    __syncthreads();
    if (g < N_NODES && perm) perm[binoff[d] + lbase[d] + myoff] = g;
}

// pass A: scatter edges into their sender-bucket's CSR region (staging).
// Block-local LDS histogram + rank -> per-(block,bucket) contiguous writes.
__global__ void bucket_scatter(const int* __restrict__ senders,
                               const int* __restrict__ receivers,
                               const float* __restrict__ weights,
                               int* __restrict__ bfill,
                               int* __restrict__ stg_s,
                               int2* __restrict__ stg_rw) {
    __shared__ int lcnt[NBUCK];
    __shared__ int lbase[NBUCK];
    int t = threadIdx.x;              // blockDim == NBUCK == 256
    lcnt[t] = 0;
    __syncthreads();
    int base = blockIdx.x * TA;
    for (int k = t; k < TA; k += 256) {
        int e = base + k;
        if (e < N_EDGES) atomicAdd(&lcnt[senders[e] >> 9], 1);
    }
    __syncthreads();
    int c = lcnt[t];
    if (c) lbase[t] = atomicAdd(&bfill[t], c);
    __syncthreads();
    lcnt[t] = 0;
    __syncthreads();
    for (int k = t; k < TA; k += 256) {
        int e = base + k;
        if (e < N_EDGES) {
            int s = senders[e];
            int b = s >> 9;
            int pos = lbase[b] + atomicAdd(&lcnt[b], 1);
            stg_s[pos] = s;
            stg_rw[pos] = make_int2(receivers[e], __float_as_int(weights[e]));
        }
    }
}

// pass B: LDS bucket sort. One block per bucket: stage the bucket's final
// edata image in LDS (rank via LDS atomics on 512 per-node counters), then
// copy LDS->global fully coalesced. No global atomics, no random global
// writes. Fallback (bucket > CAP, ~impossible for random data): old
// atomic-decrement path (cnt is intact — LDS path never touches it).
__global__ void __launch_bounds__(256, 1)
bucket_sort(const int* __restrict__ stg_s,
            const int2* __restrict__ stg_rw,
            const int* __restrict__ rowptr,
            int* __restrict__ cnt,
            int2* __restrict__ edata) {
    __shared__ int lcnt[512];
    __shared__ int2 lrw[CAP];        // 114.7 KB
    int b = blockIdx.x;
    int nbase = b << 9;
    int nend = nbase + 512; if (nend > N_NODES) nend = N_NODES;
    int ebase = rowptr[nbase];
    int eend = rowptr[nend];
    int m = eend - ebase;
    int t = threadIdx.x;

    if (m <= CAP) {
        for (int k = t; k < 512; k += 256) lcnt[k] = 0;
        __syncthreads();
        for (int k = t; k < m; k += 256) {
            int s = stg_s[ebase + k];
            int rank = atomicAdd(&lcnt[s - nbase], 1);
            lrw[(rowptr[s] - ebase) + rank] = stg_rw[ebase + k];
        }
        __syncthreads();
        for (int k = t; k < m; k += 256) {
            edata[ebase + k] = lrw[k];
        }
    } else {
        for (int k = t; k < m; k += 256) {
            int s = stg_s[ebase + k];
            int old = atomicAdd(&cnt[s], -1);
            edata[rowptr[s] + old - 1] = stg_rw[ebase + k];
        }
    }
}

// ===========================================================================
// fast fp64 rsqrt: fp32 seed + one fp64 Newton (rel err ~3e-14)
// ===========================================================================
__device__ __forceinline__ double fast_rsqrt(double x) {
    double y = (double)rsqrtf((float)x);
    y = y * fma(-0.5 * x, y * y, 1.5);
    return y;
}

// f0(cd) = acos(cd)/sqrt(1-cd^2), fp64. NUMERICS FROZEN since round 7.
__device__ __forceinline__ double theta_over_sin(double cd) {
    double acd = fabs(cd);
    bool mid = (acd <= 0.5);
    double z = mid ? (cd * cd) : (0.5 * (1.0 - acd));   // z in [0, 0.25]
    double A = 0.008390335809943149;                    // asin(sqrt(z))/sqrt(z)
    A = fma(A, z, 0.009761609529194078);
    A = fma(A, z, 0.011551800896139706);
    A = fma(A, z, 0.013964843750);
    A = fma(A, z, 0.017352764423076924);
    A = fma(A, z, 0.022372159090909092);
    A = fma(A, z, 0.030381944444444444);
    A = fma(A, z, 0.044642857142857144);
    A = fma(A, z, 0.075);
    A = fma(A, z, 0.16666666666666666);
    A = fma(A, z, 1.0);
    double R = fast_rsqrt(1.0 - z);
    if (mid) return (1.5707963267948966 - cd * A) * R;
    double AR = A * R;
    if (cd > 0.0) return AR;
    double Rz = fast_rsqrt(z);
    return fma(1.5707963267948966 * Rz, R, -AR);
}

// ===========================================================================
// Fused flow step — EXACT round-7 structure (measured local optimum; r8-r10
// pipelining/unroll/nt variants all regressed). 4 nodes/wave, lane = c+16*q.
// ===========================================================================
template <typename TI, typename TO>
__global__ void flow_kernel(const TI* __restrict__ x,
                            const int* __restrict__ rowptr,
                            const int2* __restrict__ edata,
                            const int* __restrict__ perm,
                            const float* __restrict__ t_sqrt,
                            const float* __restrict__ alpha_sqrt,
                            const float* __restrict__ beta_sqrt,
                            TO* __restrict__ xout) {
    int wave = threadIdx.x >> 6;                  // 4 waves / block
    int lane = threadIdx.x & 63;
    int q = lane >> 4;
    int c = lane & 15;
    int slot = (blockIdx.x * 4 + wave) * 4 + q;   // 16 nodes / block, exact
    int i = perm ? perm[slot] : slot;

    int beg = rowptr[i];
    int end = rowptr[i + 1];

    const TI* xi = x + ((size_t)i * N_CH + c) * DIM;
    double ax = (double)xi[0], ay = (double)xi[1], az = (double)xi[2];

    double sx = 0.0, sy = 0.0, sz = 0.0, sw = 0.0;
    for (int k = beg; k < end; ++k) {
        int2 ed = edata[k];
        int r = ed.x;
        double w = (double)__int_as_float(ed.y);
        const TI* xr = x + ((size_t)r * N_CH + c) * DIM;
        double bx = (double)xr[0], by = (double)xr[1], bz = (double)xr[2];

        double cd = ax * bx + ay * by + az * bz;
        cd = fmin(fmax(cd, -1.0 + 1e-7), 1.0 - 1e-7);
        double f = w * theta_over_sin(cd);

        sx += f * (bx - cd * ax);
        sy += f * (by - cd * ay);
        sz += f * (bz - cd * az);
        sw += w;
    }

    double dg = sw + 1e-12;
    double inv = 1.0 / dg;
    double vx = -sx * inv, vy = -sy * inv, vz = -sz * inv;

    double t = (double)t_sqrt[c];     t = (t * t) / (double)N_STEPS;
    double a = (double)alpha_sqrt[c]; a = a * a;
    double b = (double)beta_sqrt[c];  b = b * b;

    double nrm = sqrt(vx * vx + vy * vy + vz * vz + EPS_D);
    double d = 1.0 / (1.0 + exp(-b * (nrm - a)));
    double scale = (nrm * d <= 1.0) ? d : (1.0 / nrm);
    double fs = -scale * t;
    vx *= fs; vy *= fs; vz *= fs;

    double n = sqrt(vx * vx + vy * vy + vz * vz + 1e-16);
    double cn = cos(n);
    double sf = sin(n) / n;

    TO* xo = xout + ((size_t)i * N_CH + c) * DIM;
    xo[0] = (TO)(cn * ax + sf * vx);
    xo[1] = (TO)(cn * ay + sf * vy);
    xo[2] = (TO)(cn * az + sf * vz);
}

// ===========================================================================
// Fallback (round-1 fp32 atomic path, which passed) if d_ws too small
// ===========================================================================
__global__ void deg_kernel(const int* __restrict__ senders,
                           const float* __restrict__ weights,
                           float* __restrict__ deg) {
    int e = blockIdx.x * blockDim.x + threadIdx.x;
    if (e < N_EDGES) atomicAdd(&deg[senders[e]], weights[e]);
}

__global__ void edge_kernel(const float* __restrict__ x,
                            const int* __restrict__ senders,
                            const int* __restrict__ receivers,
                            const float* __restrict__ weights,
                            float* __restrict__ agg) {
    unsigned int tid = blockIdx.x * blockDim.x + threadIdx.x;
    if (tid >= (unsigned int)N_EDGES * N_CH) return;
    unsigned int e = tid >> 4;
    unsigned int c = tid & 15u;
    int s = senders[e];
    int r = receivers[e];
    float w = weights[e];
    const float* xs = x + ((size_t)s * N_CH + c) * DIM;
    const float* xr = x + ((size_t)r * N_CH + c) * DIM;
    float ax = xs[0], ay = xs[1], az = xs[2];
    float bx = xr[0], by = xr[1], bz = xr[2];
    float cd = ax * bx + ay * by + az * bz;
    cd = fminf(fmaxf(cd, -1.0f + 1e-7f), 1.0f - 1e-7f);
    float theta = acosf(cd);
    float sn = sqrtf(fmaxf(1.0f - cd * cd, 0.0f));
    float f = w * theta / sn;
    float* ag = agg + ((size_t)s * N_CH + c) * DIM;
    atomicAdd(&ag[0], f * (bx - cd * ax));
    atomicAdd(&ag[1], f * (by - cd * ay));
    atomicAdd(&ag[2], f * (bz - cd * az));
}

__global__ void node_kernel(const float* __restrict__ xin,
                            const float* __restrict__ agg,
                            const float* __restrict__ deg,
                            const float* __restrict__ t_sqrt,
                            const float* __restrict__ alpha_sqrt,
                            const float* __restrict__ beta_sqrt,
                            float* __restrict__ xout) {
    unsigned int tid = blockIdx.x * blockDim.x + threadIdx.x;
    if (tid >= (unsigned int)N_NODES * N_CH) return;
    unsigned int i = tid >> 4;
    unsigned int c = tid & 15u;
    float dg = deg[i] + 1e-12f;
    const float* ag = agg + (size_t)tid * DIM;
    float vx = -ag[0] / dg, vy = -ag[1] / dg, vz = -ag[2] / dg;
    float t = t_sqrt[c]; t = (t * t) * (1.0f / N_STEPS);
    float a = alpha_sqrt[c]; a = a * a;
    float b = beta_sqrt[c]; b = b * b;
    float nrm = sqrtf(vx * vx + vy * vy + vz * vz + 1.1920929e-7f);
    float d = 1.0f / (1.0f + __expf(-b * (nrm - a)));
    float scale = (nrm * d <= 1.0f) ? d : (1.0f / nrm);
    float fs = -scale * t;
    vx *= fs; vy *= fs; vz *= fs;
    const float* xi = xin + (size_t)tid * DIM;
    float axx = xi[0], ayy = xi[1], azz = xi[2];
    float n = sqrtf(vx * vx + vy * vy + vz * vz + 1e-16f);
    float cn = cosf(n);
    float sf = sinf(n) / n;
    float* xo = xout + (size_t)tid * DIM;
    xo[0] = cn * axx + sf * vx;
    xo[1] = cn * ayy + sf * vy;
    xo[2] = cn * azz + sf * vz;
}

extern "C" void kernel_launch(void* const* d_in, const int* in_sizes, int n_in,
                              void* d_out, int out_size, void* d_ws, size_t ws_size,
                              hipStream_t stream) {
    const float* nodes      = (const float*)d_in[0];
    const int*   senders    = (const int*)d_in[1];
    const int*   receivers  = (const int*)d_in[2];
    const float* weights    = (const float*)d_in[3];
    const float* t_sqrt     = (const float*)d_in[4];
    const float* alpha_sqrt = (const float*)d_in[5];
    const float* beta_sqrt  = (const float*)d_in[6];
    float* out = (float*)d_out;

    const size_t AL = 255;
    const size_t xtmp_b   = (size_t)N_NODES * N_CH * DIM * sizeof(double);   // 38.4 MB
    const size_t rowptr_b = (((size_t)(N_NODES + 1) * sizeof(int)) + AL) & ~AL;
    const size_t cnt_b    = (((size_t)N_NODES * sizeof(int)) + AL) & ~AL;
    const size_t bins_b   = 2048;   // bins[64]|binoff[64]|binfill[64]|bfill[256]
    const size_t part_b   = 4096;
    const size_t perm_b   = (((size_t)N_NODES * sizeof(int)) + AL) & ~AL;
    const size_t edata_b  = (size_t)N_EDGES * sizeof(int2);                  // 12.8 MB
    const size_t need_sorted = xtmp_b + rowptr_b + cnt_b + bins_b + part_b + perm_b + edata_b;
    const size_t need_plain  = xtmp_b + rowptr_b + cnt_b + bins_b + part_b + edata_b;

    if (ws_size >= need_plain) {
        bool sorted = (ws_size >= need_sorted);
        char* p = (char*)d_ws;
        double* xtmp  = (double*)p;           p += xtmp_b;
        int*   rowptr = (int*)p;              p += rowptr_b;
        int*   cnt    = (int*)p;              p += cnt_b;
        int*   bins   = (int*)p;              // [0..63] counts
        int*   binoff = bins + 64;
        int*   binfill= bins + 128;
        int*   bfill  = bins + 192;           p += bins_b;
        int*   part   = (int*)p;              p += part_b;
        int*   perm   = nullptr;
        if (sorted) { perm = (int*)p;         p += perm_b; }
        int2*  edata  = (int2*)p;

        // staging aliases xtmp (dead until flow step 1; pass B completes first)
        int2*  stg_rw = (int2*)xtmp;                         // 12.8 MB
        int*   stg_s  = (int*)((char*)xtmp + edata_b);       //  6.4 MB

        // zero cnt + bins[0..63] in one memset (adjacent)
        hipMemsetAsync(cnt, 0, cnt_b + 256, stream);
        hist_kernel<<<(N_EDGES / 4 + 255) / 256, 256, 0, stream>>>(
            (const int4*)senders, cnt);
        scan_partials_dhist<<<NBLK, PB, 0, stream>>>(cnt, part, bins);
        scan_mid_fused<<<1, 128, 0, stream>>>(part, rowptr, bins, binoff, binfill);
        scan_apply_dscatter<<<NBLK, PB, 0, stream>>>(cnt, part, rowptr,
                                                     binoff, binfill, perm, bfill);
        bucket_scatter<<<NBLK_A, NBUCK, 0, stream>>>(senders, receivers, weights,
                                                     bfill, stg_s, stg_rw);
        bucket_sort<<<NBUCK_LIVE, 256, 0, stream>>>(stg_s, stg_rw, rowptr, cnt, edata);

        int grid = N_NODES / 16;   // 6250, exact
        flow_kernel<float, double><<<grid, 256, 0, stream>>>(
            nodes, rowptr, edata, perm, t_sqrt, alpha_sqrt, beta_sqrt, xtmp);
        flow_kernel<double, float><<<grid, 256, 0, stream>>>(
            xtmp, rowptr, edata, perm, t_sqrt, alpha_sqrt, beta_sqrt, out);
    } else {
        // fallback: round-1 fp32 atomic-scatter path (passed at 1.3e-2)
        float* agg = (float*)d_ws;
        float* deg = agg + (size_t)N_NODES * N_CH * DIM;
        hipMemsetAsync(deg, 0, N_NODES * sizeof(float), stream);
        deg_kernel<<<(N_EDGES + 255) / 256, 256, 0, stream>>>(senders, weights, deg);
        const float* xin = nodes;
        for (int step = 0; step < N_STEPS; ++step) {
            hipMemsetAsync(agg, 0, (size_t)N_NODES * N_CH * DIM * sizeof(float), stream);
            unsigned int n_ec = (unsigned int)N_EDGES * N_CH;
            edge_kernel<<<(n_ec + 255) / 256, 256, 0, stream>>>(xin, senders, receivers,
                                                                weights, agg);
            unsigned int n_nc = (unsigned int)N_NODES * N_CH;
            node_kernel<<<(n_nc + 255) / 256, 256, 0, stream>>>(xin, agg, deg, t_sqrt,
                                                                alpha_sqrt, beta_sqrt, out);
            xin = out;
        }
    }
}

// Round 14
// 315.763 us; speedup vs baseline: 1.2899x; 1.0562x over previous
//
#include <hip/hip_runtime.h>

#define N_NODES 100000
#define N_CH 16
#define DIM 3
#define N_EDGES 1600000
#define N_STEPS 2
// float32 machine eps (reference wraps jnp.finfo(float32).eps)
#define EPS_D 1.1920928955078125e-7

#define PB 1024
#define NBLK ((N_NODES + PB - 1) / PB)   // 98
#define DBINS 64
#define NBUCK 256                        // sender buckets of 512 nodes (196 live)
#define NBUCK_LIVE ((N_NODES + 511) / 512)   // 196
#define TA 4096                          // edges per block, count/scatter passes
#define NBLK_A ((N_EDGES + TA - 1) / TA) // 391
#define CAP 14336                        // LDS edge capacity per bucket (114.7 KB)

// ===========================================================================
// CSR build: (node-hist + bucket-count -> pcnt) -> (partials+degree-hist)
//            -> (mid-scan+bin-scan) -> (apply + perm + bucket-base harvest)
//            -> packed bucket scatter -> LDS bucket sort
// ===========================================================================

// node histogram + per-block bucket counts (one pass over senders)
__global__ void count_kernel(const int4* __restrict__ senders4,
                             int* __restrict__ cnt,
                             int* __restrict__ pcnt) {
    __shared__ int lc[NBUCK];
    int t = threadIdx.x;
    lc[t] = 0;
    __syncthreads();
    int base4 = blockIdx.x * (TA / 4);
    for (int k = t; k < TA / 4; k += 256) {
        int idx = base4 + k;
        if (idx < N_EDGES / 4) {
            int4 s = senders4[idx];
            atomicAdd(&cnt[s.x], 1);
            atomicAdd(&cnt[s.y], 1);
            atomicAdd(&cnt[s.z], 1);
            atomicAdd(&cnt[s.w], 1);
            atomicAdd(&lc[s.x >> 9], 1);
            atomicAdd(&lc[s.y >> 9], 1);
            atomicAdd(&lc[s.z >> 9], 1);
            atomicAdd(&lc[s.w >> 9], 1);
        }
    }
    __syncthreads();
    pcnt[blockIdx.x * NBUCK + t] = lc[t];
}

// per-block sums of cnt + degree histogram (fused)
__global__ void scan_partials_dhist(const int* __restrict__ cnt,
                                    int* __restrict__ part,
                                    int* __restrict__ bins) {
    __shared__ int sh[PB];
    __shared__ int lb[DBINS];
    int t = threadIdx.x;
    if (t < DBINS) lb[t] = 0;
    int g = blockIdx.x * PB + t;
    int v = (g < N_NODES) ? cnt[g] : 0;
    sh[t] = v;
    __syncthreads();
    for (int off = PB / 2; off > 0; off >>= 1) {
        if (t < off) sh[t] += sh[t + off];
        __syncthreads();
    }
    if (t == 0) part[blockIdx.x] = sh[0];
    if (g < N_NODES) {
        int d = (v > DBINS - 1) ? (DBINS - 1) : v;
        atomicAdd(&lb[d], 1);
    }
    __syncthreads();
    if (t < DBINS && lb[t]) atomicAdd(&bins[t], lb[t]);
}

// single block: exclusive-scan the NBLK partials + exclusive-scan bins (fused)
__global__ void scan_mid_fused(int* __restrict__ part,
                               int* __restrict__ rowptr,
                               const int* __restrict__ bins,
                               int* __restrict__ binoff,
                               int* __restrict__ binfill) {
    __shared__ int sh[128];
    int t = threadIdx.x;
    int v = (t < NBLK) ? part[t] : 0;
    sh[t] = v;
    __syncthreads();
    for (int off = 1; off < 128; off <<= 1) {
        int u = (t >= off) ? sh[t - off] : 0;
        __syncthreads();
        sh[t] += u;
        __syncthreads();
    }
    if (t < NBLK) part[t] = sh[t] - v;
    if (t == NBLK - 1) rowptr[N_NODES] = sh[t];
    if (t < DBINS) {
        int bv = bins[t];
        int s = bv;
        for (int off = 1; off < DBINS; off <<= 1) {
            int u = __shfl_up(s, off, 64);
            if (t >= off) s += u;
        }
        binoff[t] = s - bv;
        binfill[t] = 0;
    }
}

// rowptr apply + degree-sorted perm scatter + bucket-base harvest (fused)
__global__ void scan_apply_dscatter(const int* __restrict__ cnt,
                                    const int* __restrict__ part,
                                    int* __restrict__ rowptr,
                                    const int* __restrict__ binoff,
                                    int* __restrict__ binfill,
                                    int* __restrict__ perm,
                                    int* __restrict__ bfill) {
    __shared__ int sh[PB];
    __shared__ int lcnt[DBINS];
    __shared__ int lbase[DBINS];
    int t = threadIdx.x;
    if (t < DBINS) lcnt[t] = 0;
    int g = blockIdx.x * PB + t;
    int v = (g < N_NODES) ? cnt[g] : 0;
    sh[t] = v;
    __syncthreads();
    for (int off = 1; off < PB; off <<= 1) {
        int u = (t >= off) ? sh[t - off] : 0;
        __syncthreads();
        sh[t] += u;
        __syncthreads();
    }
    if (g < N_NODES) {
        int rp = part[blockIdx.x] + sh[t] - v;
        rowptr[g] = rp;
        if ((g & 511) == 0) bfill[g >> 9] = rp;   // bucket base = rowptr[b*512]
    }
    int d = 0, myoff = 0;
    if (g < N_NODES) {
        d = (v > DBINS - 1) ? (DBINS - 1) : v;
        myoff = atomicAdd(&lcnt[d], 1);
    }
    __syncthreads();
    if (t < DBINS && lcnt[t]) lbase[t] = atomicAdd(&binfill[t], lcnt[t]);
    __syncthreads();
    if (g < N_NODES && perm) perm[binoff[d] + lbase[d] + myoff] = g;
}

// packed bucket scatter: uses precomputed pcnt (no second count pass).
// staging word0 = receiver | (sender_within_bucket << 17), word1 = w bits.
__global__ void scatter_kernel(const int* __restrict__ senders,
                               const int* __restrict__ receivers,
                               const float* __restrict__ weights,
                               const int* __restrict__ pcnt,
                               int* __restrict__ bfill,
                               int2* __restrict__ stg) {
    __shared__ int lbase[NBUCK];
    __shared__ int lcnt[NBUCK];
    int t = threadIdx.x;              // blockDim == NBUCK == 256
    int c = pcnt[blockIdx.x * NBUCK + t];
    if (c) lbase[t] = atomicAdd(&bfill[t], c);
    lcnt[t] = 0;
    __syncthreads();
    int base = blockIdx.x * TA;
    for (int k = t; k < TA; k += 256) {
        int e = base + k;
        if (e < N_EDGES) {
            int s = senders[e];
            int b = s >> 9;
            int pos = lbase[b] + atomicAdd(&lcnt[b], 1);
            stg[pos] = make_int2(receivers[e] | ((s & 511) << 17),
                                 __float_as_int(weights[e]));
        }
    }
}

// LDS bucket sort: one block per bucket; rank via LDS atomics on 512
// per-node counters, build the bucket's final edata image in LDS, copy out
// coalesced. Unpacks staging, writes clean (r, w) edata for flow.
// Fallback (bucket > CAP, ~impossible): atomic-decrement path (cnt intact).
__global__ void __launch_bounds__(256, 1)
bucket_sort(const int2* __restrict__ stg,
            const int* __restrict__ rowptr,
            int* __restrict__ cnt,
            int2* __restrict__ edata) {
    __shared__ int lcnt[512];
    __shared__ int2 lrw[CAP];        // 114.7 KB
    int b = blockIdx.x;
    int nbase = b << 9;
    int nend = nbase + 512; if (nend > N_NODES) nend = N_NODES;
    int ebase = rowptr[nbase];
    int eend = rowptr[nend];
    int m = eend - ebase;
    int t = threadIdx.x;

    if (m <= CAP) {
        for (int k = t; k < 512; k += 256) lcnt[k] = 0;
        __syncthreads();
        for (int k = t; k < m; k += 256) {
            int2 ed = stg[ebase + k];
            int sl = ((unsigned)ed.x) >> 17;
            int s = nbase + sl;
            int rank = atomicAdd(&lcnt[sl], 1);
            lrw[(rowptr[s] - ebase) + rank] = make_int2(ed.x & 0x1FFFF, ed.y);
        }
        __syncthreads();
        for (int k = t; k < m; k += 256) {
            edata[ebase + k] = lrw[k];
        }
    } else {
        for (int k = t; k < m; k += 256) {
            int2 ed = stg[ebase + k];
            int s = nbase + (((unsigned)ed.x) >> 17);
            int old = atomicAdd(&cnt[s], -1);
            edata[rowptr[s] + old - 1] = make_int2(ed.x & 0x1FFFF, ed.y);
        }
    }
}

// ===========================================================================
// fast fp64 rsqrt: fp32 seed + one fp64 Newton (rel err ~3e-14)
// ===========================================================================
__device__ __forceinline__ double fast_rsqrt(double x) {
    double y = (double)rsqrtf((float)x);
    y = y * fma(-0.5 * x, y * y, 1.5);
    return y;
}

// f0(cd) = acos(cd)/sqrt(1-cd^2), fp64. NUMERICS FROZEN since round 7.
__device__ __forceinline__ double theta_over_sin(double cd) {
    double acd = fabs(cd);
    bool mid = (acd <= 0.5);
    double z = mid ? (cd * cd) : (0.5 * (1.0 - acd));   // z in [0, 0.25]
    double A = 0.008390335809943149;                    // asin(sqrt(z))/sqrt(z)
    A = fma(A, z, 0.009761609529194078);
    A = fma(A, z, 0.011551800896139706);
    A = fma(A, z, 0.013964843750);
    A = fma(A, z, 0.017352764423076924);
    A = fma(A, z, 0.022372159090909092);
    A = fma(A, z, 0.030381944444444444);
    A = fma(A, z, 0.044642857142857144);
    A = fma(A, z, 0.075);
    A = fma(A, z, 0.16666666666666666);
    A = fma(A, z, 1.0);
    double R = fast_rsqrt(1.0 - z);
    if (mid) return (1.5707963267948966 - cd * A) * R;
    double AR = A * R;
    if (cd > 0.0) return AR;
    double Rz = fast_rsqrt(z);
    return fma(1.5707963267948966 * Rz, R, -AR);
}

// ===========================================================================
// Fused flow step — round-7 loop structure (measured local optimum), with
// 32-bit address arithmetic (r*48 < 2^23, no overflow -> compiler emits
// 32-bit shifts/adds instead of 64-bit mads). FP arithmetic untouched.
// ===========================================================================
template <typename TI, typename TO>
__global__ void flow_kernel(const TI* __restrict__ x,
                            const int* __restrict__ rowptr,
                            const int2* __restrict__ edata,
                            const int* __restrict__ perm,
                            const float* __restrict__ t_sqrt,
                            const float* __restrict__ alpha_sqrt,
                            const float* __restrict__ beta_sqrt,
                            TO* __restrict__ xout) {
    int wave = threadIdx.x >> 6;                  // 4 waves / block
    int lane = threadIdx.x & 63;
    int q = lane >> 4;
    int c = lane & 15;
    int slot = (blockIdx.x * 4 + wave) * 4 + q;   // 16 nodes / block, exact
    int i = perm ? perm[slot] : slot;
    int c3 = c * DIM;

    int beg = rowptr[i];
    int end = rowptr[i + 1];

    const TI* xi = x + (i * (N_CH * DIM) + c3);
    double ax = (double)xi[0], ay = (double)xi[1], az = (double)xi[2];

    double sx = 0.0, sy = 0.0, sz = 0.0, sw = 0.0;
    for (int k = beg; k < end; ++k) {
        int2 ed = edata[k];
        int r = ed.x;
        double w = (double)__int_as_float(ed.y);
        const TI* xr = x + (r * (N_CH * DIM) + c3);
        double bx = (double)xr[0], by = (double)xr[1], bz = (double)xr[2];

        double cd = ax * bx + ay * by + az * bz;
        cd = fmin(fmax(cd, -1.0 + 1e-7), 1.0 - 1e-7);
        double f = w * theta_over_sin(cd);

        sx += f * (bx - cd * ax);
        sy += f * (by - cd * ay);
        sz += f * (bz - cd * az);
        sw += w;
    }

    double dg = sw + 1e-12;
    double inv = 1.0 / dg;
    double vx = -sx * inv, vy = -sy * inv, vz = -sz * inv;

    double t = (double)t_sqrt[c];     t = (t * t) / (double)N_STEPS;
    double a = (double)alpha_sqrt[c]; a = a * a;
    double b = (double)beta_sqrt[c];  b = b * b;

    double nrm = sqrt(vx * vx + vy * vy + vz * vz + EPS_D);
    double d = 1.0 / (1.0 + exp(-b * (nrm - a)));
    double scale = (nrm * d <= 1.0) ? d : (1.0 / nrm);
    double fs = -scale * t;
    vx *= fs; vy *= fs; vz *= fs;

    double n = sqrt(vx * vx + vy * vy + vz * vz + 1e-16);
    double cn = cos(n);
    double sf = sin(n) / n;

    TO* xo = xout + (i * (N_CH * DIM) + c3);
    xo[0] = (TO)(cn * ax + sf * vx);
    xo[1] = (TO)(cn * ay + sf * vy);
    xo[2] = (TO)(cn * az + sf * vz);
}

// ===========================================================================
// Fallback (round-1 fp32 atomic path, which passed) if d_ws too small
// ===========================================================================
__global__ void deg_kernel(const int* __restrict__ senders,
                           const float* __restrict__ weights,
                           float* __restrict__ deg) {
    int e = blockIdx.x * blockDim.x + threadIdx.x;
    if (e < N_EDGES) atomicAdd(&deg[senders[e]], weights[e]);
}

__global__ void edge_kernel(const float* __restrict__ x,
                            const int* __restrict__ senders,
                            const int* __restrict__ receivers,
                            const float* __restrict__ weights,
                            float* __restrict__ agg) {
    unsigned int tid = blockIdx.x * blockDim.x + threadIdx.x;
    if (tid >= (unsigned int)N_EDGES * N_CH) return;
    unsigned int e = tid >> 4;
    unsigned int c = tid & 15u;
    int s = senders[e];
    int r = receivers[e];
    float w = weights[e];
    const float* xs = x + ((size_t)s * N_CH + c) * DIM;
    const float* xr = x + ((size_t)r * N_CH + c) * DIM;
    float ax = xs[0], ay = xs[1], az = xs[2];
    float bx = xr[0], by = xr[1], bz = xr[2];
    float cd = ax * bx + ay * by + az * bz;
    cd = fminf(fmaxf(cd, -1.0f + 1e-7f), 1.0f - 1e-7f);
    float theta = acosf(cd);
    float sn = sqrtf(fmaxf(1.0f - cd * cd, 0.0f));
    float f = w * theta / sn;
    float* ag = agg + ((size_t)s * N_CH + c) * DIM;
    atomicAdd(&ag[0], f * (bx - cd * ax));
    atomicAdd(&ag[1], f * (by - cd * ay));
    atomicAdd(&ag[2], f * (bz - cd * az));
}

__global__ void node_kernel(const float* __restrict__ xin,
                            const float* __restrict__ agg,
                            const float* __restrict__ deg,
                            const float* __restrict__ t_sqrt,
                            const float* __restrict__ alpha_sqrt,
                            const float* __restrict__ beta_sqrt,
                            float* __restrict__ xout) {
    unsigned int tid = blockIdx.x * blockDim.x + threadIdx.x;
    if (tid >= (unsigned int)N_NODES * N_CH) return;
    unsigned int i = tid >> 4;
    unsigned int c = tid & 15u;
    float dg = deg[i] + 1e-12f;
    const float* ag = agg + (size_t)tid * DIM;
    float vx = -ag[0] / dg, vy = -ag[1] / dg, vz = -ag[2] / dg;
    float t = t_sqrt[c]; t = (t * t) * (1.0f / N_STEPS);
    float a = alpha_sqrt[c]; a = a * a;
    float b = beta_sqrt[c]; b = b * b;
    float nrm = sqrtf(vx * vx + vy * vy + vz * vz + 1.1920929e-7f);
    float d = 1.0f / (1.0f + __expf(-b * (nrm - a)));
    float scale = (nrm * d <= 1.0f) ? d : (1.0f / nrm);
    float fs = -scale * t;
    vx *= fs; vy *= fs; vz *= fs;
    const float* xi = xin + (size_t)tid * DIM;
    float axx = xi[0], ayy = xi[1], azz = xi[2];
    float n = sqrtf(vx * vx + vy * vy + vz * vz + 1e-16f);
    float cn = cosf(n);
    float sf = sinf(n) / n;
    float* xo = xout + (size_t)tid * DIM;
    xo[0] = cn * axx + sf * vx;
    xo[1] = cn * ayy + sf * vy;
    xo[2] = cn * azz + sf * vz;
}

extern "C" void kernel_launch(void* const* d_in, const int* in_sizes, int n_in,
                              void* d_out, int out_size, void* d_ws, size_t ws_size,
                              hipStream_t stream) {
    const float* nodes      = (const float*)d_in[0];
    const int*   senders    = (const int*)d_in[1];
    const int*   receivers  = (const int*)d_in[2];
    const float* weights    = (const float*)d_in[3];
    const float* t_sqrt     = (const float*)d_in[4];
    const float* alpha_sqrt = (const float*)d_in[5];
    const float* beta_sqrt  = (const float*)d_in[6];
    float* out = (float*)d_out;

    const size_t AL = 255;
    const size_t xtmp_b   = (size_t)N_NODES * N_CH * DIM * sizeof(double);   // 38.4 MB
    const size_t rowptr_b = (((size_t)(N_NODES + 1) * sizeof(int)) + AL) & ~AL;
    const size_t cnt_b    = (((size_t)N_NODES * sizeof(int)) + AL) & ~AL;
    const size_t bins_b   = 2048;   // bins[64]|binoff[64]|binfill[64]|bfill[256]
    const size_t part_b   = 4096;
    const size_t perm_b   = (((size_t)N_NODES * sizeof(int)) + AL) & ~AL;
    const size_t edata_b  = (size_t)N_EDGES * sizeof(int2);                  // 12.8 MB
    const size_t need_sorted = xtmp_b + rowptr_b + cnt_b + bins_b + part_b + perm_b + edata_b;
    const size_t need_plain  = xtmp_b + rowptr_b + cnt_b + bins_b + part_b + edata_b;

    if (ws_size >= need_plain) {
        bool sorted = (ws_size >= need_sorted);
        char* p = (char*)d_ws;
        double* xtmp  = (double*)p;           p += xtmp_b;
        int*   rowptr = (int*)p;              p += rowptr_b;
        int*   cnt    = (int*)p;              p += cnt_b;
        int*   bins   = (int*)p;              // [0..63] counts
        int*   binoff = bins + 64;
        int*   binfill= bins + 128;
        int*   bfill  = bins + 192;           p += bins_b;
        int*   part   = (int*)p;              p += part_b;
        int*   perm   = nullptr;
        if (sorted) { perm = (int*)p;         p += perm_b; }
        int2*  edata  = (int2*)p;

        // staging + pcnt alias xtmp (dead until flow step 1):
        //   stg  : [0, 12.8 MB)          packed (r | s_local<<17, w)
        //   pcnt : [16 MB, 16.4 MB)      per-(block,bucket) counts
        int2*  stg  = (int2*)xtmp;
        int*   pcnt = (int*)((char*)xtmp + (16u << 20));

        // zero cnt + bins[0..63] in one memset (adjacent)
        hipMemsetAsync(cnt, 0, cnt_b + 256, stream);
        count_kernel<<<NBLK_A, NBUCK, 0, stream>>>((const int4*)senders, cnt, pcnt);
        scan_partials_dhist<<<NBLK, PB, 0, stream>>>(cnt, part, bins);
        scan_mid_fused<<<1, 128, 0, stream>>>(part, rowptr, bins, binoff, binfill);
        scan_apply_dscatter<<<NBLK, PB, 0, stream>>>(cnt, part, rowptr,
                                                     binoff, binfill, perm, bfill);
        scatter_kernel<<<NBLK_A, NBUCK, 0, stream>>>(senders, receivers, weights,
                                                     pcnt, bfill, stg);
        bucket_sort<<<NBUCK_LIVE, 256, 0, stream>>>(stg, rowptr, cnt, edata);

        int grid = N_NODES / 16;   // 6250, exact
        flow_kernel<float, double><<<grid, 256, 0, stream>>>(
            nodes, rowptr, edata, perm, t_sqrt, alpha_sqrt, beta_sqrt, xtmp);
        flow_kernel<double, float><<<grid, 256, 0, stream>>>(
            xtmp, rowptr, edata, perm, t_sqrt, alpha_sqrt, beta_sqrt, out);
    } else {
        // fallback: round-1 fp32 atomic-scatter path (passed at 1.3e-2)
        float* agg = (float*)d_ws;
        float* deg = agg + (size_t)N_NODES * N_CH * DIM;
        hipMemsetAsync(deg, 0, N_NODES * sizeof(float), stream);
        deg_kernel<<<(N_EDGES + 255) / 256, 256, 0, stream>>>(senders, weights, deg);
        const float* xin = nodes;
        for (int step = 0; step < N_STEPS; ++step) {
            hipMemsetAsync(agg, 0, (size_t)N_NODES * N_CH * DIM * sizeof(float), stream);
            unsigned int n_ec = (unsigned int)N_EDGES * N_CH;
            edge_kernel<<<(n_ec + 255) / 256, 256, 0, stream>>>(xin, senders, receivers,
                                                                weights, agg);
            unsigned int n_nc = (unsigned int)N_NODES * N_CH;
            node_kernel<<<(n_nc + 255) / 256, 256, 0, stream>>>(xin, agg, deg, t_sqrt,
                                                                alpha_sqrt, beta_sqrt, out);
            xin = out;
        }
    }
}